// Round 1
// baseline (1492.421 us; speedup 1.0000x reference)
//
#include <hip/hip_runtime.h>
#include <cstdint>
#include <cstddef>

#define HID 128

// ---------------- small transpose (weights, once per launch) ----------------
__global__ void transpose_kernel(const float* __restrict__ src, float* __restrict__ dst,
                                 int R, int C) {
  int i = blockIdx.x * blockDim.x + threadIdx.x;
  if (i < R * C) {
    int r = i / C, c = i - r * C;
    dst[c * R + r] = src[i];
  }
}

// ---------------- CSR build ----------------
__global__ void hist_kernel(const int* __restrict__ row, int* __restrict__ deg, int E) {
  for (int e = blockIdx.x * blockDim.x + threadIdx.x; e < E; e += gridDim.x * blockDim.x)
    atomicAdd(&deg[row[e]], 1);
}

__global__ __launch_bounds__(1024)
void scan_kernel(const int* __restrict__ deg, int* __restrict__ offsets,
                 int* __restrict__ cursor, int N) {
  __shared__ int sdata[1024];
  int t = threadIdx.x;
  int chunk = (N + 1023) >> 10;
  int b = t * chunk, e = min(b + chunk, N);
  int s = 0;
  for (int i = b; i < e; ++i) s += deg[i];
  sdata[t] = s;
  __syncthreads();
  for (int off = 1; off < 1024; off <<= 1) {
    int v = (t >= off) ? sdata[t - off] : 0;
    __syncthreads();
    sdata[t] += v;
    __syncthreads();
  }
  int run = (t == 0) ? 0 : sdata[t - 1];
  for (int i = b; i < e; ++i) {
    offsets[i] = run; cursor[i] = run;
    run += deg[i];
  }
  if (t == 1023) offsets[N] = sdata[1023];
}

__global__ void fill_kernel(const int* __restrict__ row, const int* __restrict__ col,
                            int* __restrict__ cursor, int* __restrict__ csr_col, int E) {
  for (int e = blockIdx.x * blockDim.x + threadIdx.x; e < E; e += gridDim.x * blockDim.x) {
    int r = row[e];
    int p = atomicAdd(&cursor[r], 1);
    csr_col[p] = col[e];
  }
}

// ---------------- edge aggregation: diff[i][d] = sum_e |h[i][d]-h[col][d]| ----
__global__ void aggregate_kernel(const float* __restrict__ h, const int* __restrict__ offsets,
                                 const int* __restrict__ csr_col, float* __restrict__ diff,
                                 int N) {
  int node = blockIdx.x * 2 + (threadIdx.x >> 7);
  int d = threadIdx.x & 127;
  if (node >= N) return;
  float hv = h[(size_t)node * HID + d];
  int e = offsets[node], end = offsets[node + 1];
  float acc = 0.f;
  int c = (e < end) ? csr_col[e] : 0;
  for (; e < end; ++e) {
    int cn = (e + 1 < end) ? csr_col[e + 1] : 0;
    acc += fabsf(hv - h[(size_t)c * HID + d]);
    c = cn;
  }
  diff[(size_t)node * HID + d] = acc;
}

// ---------------- tiled fp32 GEMM: C = relu([A1|A2] @ BT + bias), opt tau ----
// Tile: 128 rows x 128 cols, K-chunks of 32. BT is [K][128] (pre-transposed).
template<bool TAU>
__global__ __launch_bounds__(256)
void gemm_kernel(const float* __restrict__ A1, const float* __restrict__ A2,
                 const float* __restrict__ BT, const float* __restrict__ bias,
                 float* __restrict__ C, int M, int nchunks,
                 const float* __restrict__ Wt, const float* __restrict__ bt,
                 float* __restrict__ tau_out) {
  __shared__ float As[32][132];   // [k][i], padded leading dim
  __shared__ float Bs[32][128];   // [k][c]
  __shared__ float taured[128];
  int tid = threadIdx.x;
  int tx = tid & 15;   // col group: cols tx + 16*u
  int ty = tid >> 4;   // row group: rows ty*8 + r
  int i0 = blockIdx.x * 128;
  float acc[8][8] = {};

  for (int kc = 0; kc < nchunks; ++kc) {
    const float* A = (kc < 4) ? A1 : A2;
    int ksrc = (kc & 3) * 32;
    int kglob = kc * 32;
    #pragma unroll
    for (int q = 0; q < 4; ++q) {     // stage A (transposed into LDS)
      int f = q * 256 + tid;
      int i = f >> 3;
      int kq = (f & 7) << 2;
      int ig = i0 + i; if (ig >= M) ig = M - 1;
      float4 v = *(const float4*)(A + (size_t)ig * HID + ksrc + kq);
      As[kq + 0][i] = v.x; As[kq + 1][i] = v.y;
      As[kq + 2][i] = v.z; As[kq + 3][i] = v.w;
    }
    #pragma unroll
    for (int q = 0; q < 4; ++q) {     // stage B
      int f = q * 256 + tid;
      int k = f >> 5; int c4 = (f & 31) << 2;
      *(float4*)&Bs[k][c4] = *(const float4*)(BT + (size_t)(kglob + k) * HID + c4);
    }
    __syncthreads();
    #pragma unroll
    for (int k = 0; k < 32; ++k) {
      float a[8], b[8];
      const float4* ap = (const float4*)&As[k][ty * 8];
      float4 a0 = ap[0], a1 = ap[1];
      a[0]=a0.x; a[1]=a0.y; a[2]=a0.z; a[3]=a0.w;
      a[4]=a1.x; a[5]=a1.y; a[6]=a1.z; a[7]=a1.w;
      #pragma unroll
      for (int u = 0; u < 8; ++u) b[u] = Bs[k][tx + 16 * u];
      #pragma unroll
      for (int r = 0; r < 8; ++r)
        #pragma unroll
        for (int u = 0; u < 8; ++u)
          acc[r][u] = fmaf(a[r], b[u], acc[r][u]);
    }
    __syncthreads();
  }

  float bias_r[8], wt_r[8];
  #pragma unroll
  for (int u = 0; u < 8; ++u) { bias_r[u] = bias[tx + 16 * u]; wt_r[u] = 0.f; }
  if constexpr (TAU) {
    #pragma unroll
    for (int u = 0; u < 8; ++u) wt_r[u] = Wt[tx + 16 * u];
  }
  #pragma unroll
  for (int r = 0; r < 8; ++r) {
    int row = i0 + ty * 8 + r;
    bool ok = row < M;
    float p = 0.f;
    #pragma unroll
    for (int u = 0; u < 8; ++u) {
      float v = fmaxf(acc[r][u] + bias_r[u], 0.f);
      if (ok) C[(size_t)row * HID + tx + 16 * u] = v;
      p = fmaf(v, wt_r[u], p);
    }
    if constexpr (TAU) {
      p += __shfl_down(p, 8);
      p += __shfl_down(p, 4);
      p += __shfl_down(p, 2);
      p += __shfl_down(p, 1);
      if (tx == 0) taured[ty * 8 + r] = p;
    }
  }
  if constexpr (TAU) {
    __syncthreads();
    if (tid < 128) {
      int row = i0 + tid;
      if (row < M) {
        float pre = taured[tid] + bt[0];
        float tau = (pre > 20.f) ? pre : log1pf(expf(pre));
        tau_out[row] = tau;
      }
    }
  }
}

// ---------------- mask + compaction ----------------
// np semantics: floor(1/tau).astype(int32) overflows to INT_MIN for 1/tau >= 2^31
// -> n_updates <= 0 -> NOT masked even though tau < 0.005.
__global__ void compact_kernel(const float* __restrict__ tau, int* __restrict__ list,
                               int* __restrict__ count, int N) {
  for (int i = blockIdx.x * blockDim.x + threadIdx.x; i < N; i += gridDim.x * blockDim.x) {
    float t = tau[i];
    if (t < 0.005f && (1.0f / t) < 2147483648.0f) {
      int p = atomicAdd(count, 1);
      list[p] = i;
    }
  }
}

// ---------------- masked GRU, 16 nodes / block ----------------
__global__ __launch_bounds__(256)
void gru_kernel(const float* __restrict__ diff, float* __restrict__ h,
                const int* __restrict__ list, const int* __restrict__ count,
                const float* __restrict__ WihT, const float* __restrict__ WhhT,
                const float* __restrict__ b_ih, const float* __restrict__ b_hh) {
  int cnt = *count;
  int base = blockIdx.x * 16;
  if (base >= cnt) return;
  __shared__ float dl[16][HID];
  __shared__ float hl[16][HID];
  __shared__ int ids[16];
  int tid = threadIdx.x;
  if (tid < 16) ids[tid] = (base + tid < cnt) ? list[base + tid] : -1;
  __syncthreads();
  #pragma unroll
  for (int q = 0; q < 8; ++q) {
    int f = q * 256 + tid;
    int r = f >> 7, c = f & 127;
    int id = ids[r];
    int src = (id >= 0) ? id : 0;
    dl[r][c] = diff[(size_t)src * HID + c];
    hl[r][c] = h[(size_t)src * HID + c];
  }
  __syncthreads();
  int tx = tid & 127, ty = tid >> 7;  // tx = output dim, ty -> rows ty*8..ty*8+7
  float air[8] = {}, aiz[8] = {}, ain[8] = {}, ahr[8] = {}, ahz[8] = {}, ahn[8] = {};
  for (int k = 0; k < HID; ++k) {
    float wir = WihT[k * 384 + tx];
    float wiz = WihT[k * 384 + 128 + tx];
    float win = WihT[k * 384 + 256 + tx];
    float whr = WhhT[k * 384 + tx];
    float whz = WhhT[k * 384 + 128 + tx];
    float whn = WhhT[k * 384 + 256 + tx];
    #pragma unroll
    for (int r = 0; r < 8; ++r) {
      float dk = dl[ty * 8 + r][k];
      float hk = hl[ty * 8 + r][k];
      air[r] = fmaf(dk, wir, air[r]);
      aiz[r] = fmaf(dk, wiz, aiz[r]);
      ain[r] = fmaf(dk, win, ain[r]);
      ahr[r] = fmaf(hk, whr, ahr[r]);
      ahz[r] = fmaf(hk, whz, ahz[r]);
      ahn[r] = fmaf(hk, whn, ahn[r]);
    }
  }
  float bir = b_ih[tx], biz = b_ih[128 + tx], bin = b_ih[256 + tx];
  float bhr = b_hh[tx], bhz = b_hh[128 + tx], bhn = b_hh[256 + tx];
  #pragma unroll
  for (int r = 0; r < 8; ++r) {
    int id = ids[ty * 8 + r];
    if (id < 0) continue;
    float rg = 1.f / (1.f + expf(-((air[r] + bir) + (ahr[r] + bhr))));
    float z  = 1.f / (1.f + expf(-((aiz[r] + biz) + (ahz[r] + bhz))));
    float n  = tanhf((ain[r] + bin) + rg * (ahn[r] + bhn));
    float hv = hl[ty * 8 + r][tx];
    h[(size_t)id * HID + tx] = (1.f - z) * n + z * hv;
  }
}

// ---------------- output head: out = h @ Wo^T + bo  (wave per node) ----------
__global__ void out_kernel(const float* __restrict__ h, const float* __restrict__ Wo,
                           const float* __restrict__ bo, float* __restrict__ out, int N) {
  int g = blockIdx.x * blockDim.x + threadIdx.x;
  int node = g >> 6;
  int lane = threadIdx.x & 63;
  if (node >= N) return;
  float h0 = h[(size_t)node * HID + lane];
  float h1 = h[(size_t)node * HID + 64 + lane];
  float s0 = h0 * Wo[lane] + h1 * Wo[64 + lane];
  float s1 = h0 * Wo[128 + lane] + h1 * Wo[192 + lane];
  for (int d = 32; d; d >>= 1) {
    s0 += __shfl_down(s0, d);
    s1 += __shfl_down(s1, d);
  }
  if (lane == 0) {
    out[(size_t)node * 2 + 0] = s0 + bo[0];
    out[(size_t)node * 2 + 1] = s1 + bo[1];
  }
}

extern "C" void kernel_launch(void* const* d_in, const int* in_sizes, int n_in,
                              void* d_out, int out_size, void* d_ws, size_t ws_size,
                              hipStream_t stream) {
  const float* x    = (const float*)d_in[0];
  const int*   ei   = (const int*)d_in[1];
  const float* W_in = (const float*)d_in[2];
  const float* b_in = (const float*)d_in[3];
  const float* Wd   = (const float*)d_in[4];
  const float* bd   = (const float*)d_in[5];
  const float* Wt   = (const float*)d_in[6];
  const float* bt   = (const float*)d_in[7];
  const float* W_ih = (const float*)d_in[8];
  const float* W_hh = (const float*)d_in[9];
  const float* b_ih = (const float*)d_in[10];
  const float* b_hh = (const float*)d_in[11];
  const float* Wo   = (const float*)d_in[12];
  const float* bo   = (const float*)d_in[13];

  const int N = in_sizes[0] / HID;      // 100000
  const int E = in_sizes[1] / 2;        // 1600000
  const int* rowp = ei;
  const int* colp = ei + E;

  // workspace carve-up (256B aligned)
  char* p = (char*)d_ws;
  auto alloc = [&](size_t bytes) { void* r = (void*)p; p += (bytes + 255) & ~(size_t)255; return r; };
  float* hA     = (float*)alloc((size_t)N * HID * 4);
  float* hB     = (float*)alloc((size_t)N * HID * 4);
  float* diff   = (float*)alloc((size_t)N * HID * 4);
  float* WinT   = (float*)alloc(128 * 128 * 4);
  float* WdT0   = (float*)alloc(256 * 128 * 4);
  float* WdT1   = (float*)alloc(256 * 128 * 4);
  float* WihT   = (float*)alloc(128 * 384 * 4);
  float* WhhT   = (float*)alloc(128 * 384 * 4);
  int*   deg    = (int*)alloc((size_t)N * 4);
  int*   offs   = (int*)alloc(((size_t)N + 1) * 4);
  int*   cursor = (int*)alloc((size_t)N * 4);
  int*   csrcol = (int*)alloc((size_t)E * 4);
  float* tau0   = (float*)alloc((size_t)N * 4);
  int*   list   = (int*)alloc((size_t)N * 4);
  int*   count  = (int*)alloc(256);

  float* out_ptr = (float*)d_out;            // [N,2] flat
  float* tau_out = (float*)d_out + (size_t)N * 2;  // [N]

  // weight transposes
  transpose_kernel<<<(128 * 128 + 255) / 256, 256, 0, stream>>>(W_in, WinT, 128, 128);
  transpose_kernel<<<(128 * 256 + 255) / 256, 256, 0, stream>>>(Wd, WdT0, 128, 256);
  transpose_kernel<<<(128 * 256 + 255) / 256, 256, 0, stream>>>(Wd + 128 * 256, WdT1, 128, 256);
  transpose_kernel<<<(384 * 128 + 255) / 256, 256, 0, stream>>>(W_ih, WihT, 384, 128);
  transpose_kernel<<<(384 * 128 + 255) / 256, 256, 0, stream>>>(W_hh, WhhT, 384, 128);

  // CSR build (reused by both layers)
  hipMemsetAsync(deg, 0, (size_t)N * 4, stream);
  hist_kernel<<<(E + 255) / 256, 256, 0, stream>>>(rowp, deg, E);
  scan_kernel<<<1, 1024, 0, stream>>>(deg, offs, cursor, N);
  fill_kernel<<<(E + 255) / 256, 256, 0, stream>>>(rowp, colp, cursor, csrcol, E);

  const int gemm_blocks = (N + 127) / 128;

  // input layer: hA = relu(x @ Win^T + b_in)
  gemm_kernel<false><<<gemm_blocks, 256, 0, stream>>>(
      x, nullptr, WinT, b_in, hA, N, 4, nullptr, nullptr, nullptr);

  // ---- layer 0 ----
  aggregate_kernel<<<(N + 1) / 2, 256, 0, stream>>>(hA, offs, csrcol, diff, N);
  gemm_kernel<true><<<gemm_blocks, 256, 0, stream>>>(
      hA, diff, WdT0, bd, hB, N, 8, Wt, bt, tau0);
  hipMemsetAsync(count, 0, 4, stream);
  compact_kernel<<<(N + 255) / 256, 256, 0, stream>>>(tau0, list, count, N);
  gru_kernel<<<(N + 15) / 16, 256, 0, stream>>>(diff, hB, list, count, WihT, WhhT, b_ih, b_hh);

  // ---- layer 1 ----
  aggregate_kernel<<<(N + 1) / 2, 256, 0, stream>>>(hB, offs, csrcol, diff, N);
  gemm_kernel<true><<<gemm_blocks, 256, 0, stream>>>(
      hB, diff, WdT1, bd + 128, hA, N, 8, Wt, bt, tau_out);
  hipMemsetAsync(count, 0, 4, stream);
  compact_kernel<<<(N + 255) / 256, 256, 0, stream>>>(tau_out, list, count, N);
  gru_kernel<<<(N + 15) / 16, 256, 0, stream>>>(diff, hA, list, count, WihT, WhhT, b_ih, b_hh);

  // output head
  out_kernel<<<((size_t)N * 64 + 255) / 256, 256, 0, stream>>>(hA, Wo, bo, out_ptr, N);
}

// Round 2
// 1144.289 us; speedup vs baseline: 1.3042x; 1.3042x over previous
//
#include <hip/hip_runtime.h>
#include <cstdint>
#include <cstddef>

#define HID 128

// ---------------- small transpose (weights, once per launch) ----------------
__global__ void transpose_kernel(const float* __restrict__ src, float* __restrict__ dst,
                                 int R, int C) {
  int i = blockIdx.x * blockDim.x + threadIdx.x;
  if (i < R * C) {
    int r = i / C, c = i - r * C;
    dst[c * R + r] = src[i];
  }
}

// ---------------- CSR build ----------------
__global__ void hist_kernel(const int* __restrict__ row, int* __restrict__ deg, int E) {
  for (int e = blockIdx.x * blockDim.x + threadIdx.x; e < E; e += gridDim.x * blockDim.x)
    atomicAdd(&deg[row[e]], 1);
}

__global__ __launch_bounds__(1024)
void scan_kernel(const int* __restrict__ deg, int* __restrict__ offsets,
                 int* __restrict__ cursor, int N) {
  __shared__ int sdata[1024];
  int t = threadIdx.x;
  int chunk = (N + 1023) >> 10;
  int b = t * chunk, e = min(b + chunk, N);
  int s = 0;
  for (int i = b; i < e; ++i) s += deg[i];
  sdata[t] = s;
  __syncthreads();
  for (int off = 1; off < 1024; off <<= 1) {
    int v = (t >= off) ? sdata[t - off] : 0;
    __syncthreads();
    sdata[t] += v;
    __syncthreads();
  }
  int run = (t == 0) ? 0 : sdata[t - 1];
  for (int i = b; i < e; ++i) {
    offsets[i] = run; cursor[i] = run;
    run += deg[i];
  }
  if (t == 1023) offsets[N] = sdata[1023];
}

__global__ void fill_kernel(const int* __restrict__ row, const int* __restrict__ col,
                            int* __restrict__ cursor, int* __restrict__ csr_col, int E) {
  for (int e = blockIdx.x * blockDim.x + threadIdx.x; e < E; e += gridDim.x * blockDim.x) {
    int r = row[e];
    int p = atomicAdd(&cursor[r], 1);
    csr_col[p] = col[e];
  }
}

// ---------------- edge aggregation: diff[i][d] = sum_e |h[i][d]-h[col][d]| ----
// One wave per node; lane owns dims {lane, lane+64}. Neighbor ids staged into
// registers (coalesced csr_col load + __shfl broadcast); 4-edge unroll gives
// 8 outstanding gathers/lane (round 1 had 1 -> latency-bound at 2.8 TB/s eff).
__global__ __launch_bounds__(256)
void aggregate_kernel(const float* __restrict__ h, const int* __restrict__ offsets,
                      const int* __restrict__ csr_col, float* __restrict__ diff,
                      int N) {
  int wave = threadIdx.x >> 6;
  int lane = threadIdx.x & 63;
  int node = blockIdx.x * 4 + wave;
  if (node >= N) return;
  int start = offsets[node], end = offsets[node + 1];
  int deg = end - start;
  const float* hrow = h + (size_t)node * HID;
  float hv0 = hrow[lane], hv1 = hrow[lane + 64];
  float a0 = 0.f, a1 = 0.f;

  int batch = min(deg, 64);
  int myc = (lane < batch) ? csr_col[start + lane] : 0;
  int j = 0;
  for (; j + 4 <= batch; j += 4) {
    int c0 = __shfl(myc, j + 0);
    int c1 = __shfl(myc, j + 1);
    int c2 = __shfl(myc, j + 2);
    int c3 = __shfl(myc, j + 3);
    const float* p0 = h + (size_t)c0 * HID;
    const float* p1 = h + (size_t)c1 * HID;
    const float* p2 = h + (size_t)c2 * HID;
    const float* p3 = h + (size_t)c3 * HID;
    float x00 = p0[lane], x01 = p0[lane + 64];
    float x10 = p1[lane], x11 = p1[lane + 64];
    float x20 = p2[lane], x21 = p2[lane + 64];
    float x30 = p3[lane], x31 = p3[lane + 64];
    a0 += fabsf(hv0 - x00) + fabsf(hv0 - x10) + fabsf(hv0 - x20) + fabsf(hv0 - x30);
    a1 += fabsf(hv1 - x01) + fabsf(hv1 - x11) + fabsf(hv1 - x21) + fabsf(hv1 - x31);
  }
  for (; j < batch; ++j) {
    int c = __shfl(myc, j);
    const float* p = h + (size_t)c * HID;
    a0 += fabsf(hv0 - p[lane]);
    a1 += fabsf(hv1 - p[lane + 64]);
  }
  // rare overflow path (deg > 64): direct reads
  for (int e = start + 64; e < end; ++e) {
    int c = csr_col[e];
    const float* p = h + (size_t)c * HID;
    a0 += fabsf(hv0 - p[lane]);
    a1 += fabsf(hv1 - p[lane + 64]);
  }
  diff[(size_t)node * HID + lane] = a0;
  diff[(size_t)node * HID + lane + 64] = a1;
}

// ---------------- tiled fp32 GEMM: C = relu([A1|A2] @ BT + bias), opt tau ----
// Tile: 128 rows x 128 cols, K-chunks of 32. BT is [K][128] (pre-transposed).
template<bool TAU>
__global__ __launch_bounds__(256)
void gemm_kernel(const float* __restrict__ A1, const float* __restrict__ A2,
                 const float* __restrict__ BT, const float* __restrict__ bias,
                 float* __restrict__ C, int M, int nchunks,
                 const float* __restrict__ Wt, const float* __restrict__ bt,
                 float* __restrict__ tau_out) {
  __shared__ float As[32][132];   // [k][i], padded leading dim
  __shared__ float Bs[32][128];   // [k][c]
  __shared__ float taured[128];
  int tid = threadIdx.x;
  int tx = tid & 15;   // col group: cols tx + 16*u
  int ty = tid >> 4;   // row group: rows ty*8 + r
  int i0 = blockIdx.x * 128;
  float acc[8][8] = {};

  for (int kc = 0; kc < nchunks; ++kc) {
    const float* A = (kc < 4) ? A1 : A2;
    int ksrc = (kc & 3) * 32;
    int kglob = kc * 32;
    #pragma unroll
    for (int q = 0; q < 4; ++q) {     // stage A (transposed into LDS)
      int f = q * 256 + tid;
      int i = f >> 3;
      int kq = (f & 7) << 2;
      int ig = i0 + i; if (ig >= M) ig = M - 1;
      float4 v = *(const float4*)(A + (size_t)ig * HID + ksrc + kq);
      As[kq + 0][i] = v.x; As[kq + 1][i] = v.y;
      As[kq + 2][i] = v.z; As[kq + 3][i] = v.w;
    }
    #pragma unroll
    for (int q = 0; q < 4; ++q) {     // stage B
      int f = q * 256 + tid;
      int k = f >> 5; int c4 = (f & 31) << 2;
      *(float4*)&Bs[k][c4] = *(const float4*)(BT + (size_t)(kglob + k) * HID + c4);
    }
    __syncthreads();
    #pragma unroll
    for (int k = 0; k < 32; ++k) {
      float a[8], b[8];
      const float4* ap = (const float4*)&As[k][ty * 8];
      float4 a0 = ap[0], a1 = ap[1];
      a[0]=a0.x; a[1]=a0.y; a[2]=a0.z; a[3]=a0.w;
      a[4]=a1.x; a[5]=a1.y; a[6]=a1.z; a[7]=a1.w;
      #pragma unroll
      for (int u = 0; u < 8; ++u) b[u] = Bs[k][tx + 16 * u];
      #pragma unroll
      for (int r = 0; r < 8; ++r)
        #pragma unroll
        for (int u = 0; u < 8; ++u)
          acc[r][u] = fmaf(a[r], b[u], acc[r][u]);
    }
    __syncthreads();
  }

  float bias_r[8], wt_r[8];
  #pragma unroll
  for (int u = 0; u < 8; ++u) { bias_r[u] = bias[tx + 16 * u]; wt_r[u] = 0.f; }
  if constexpr (TAU) {
    #pragma unroll
    for (int u = 0; u < 8; ++u) wt_r[u] = Wt[tx + 16 * u];
  }
  #pragma unroll
  for (int r = 0; r < 8; ++r) {
    int row = i0 + ty * 8 + r;
    bool ok = row < M;
    float p = 0.f;
    #pragma unroll
    for (int u = 0; u < 8; ++u) {
      float v = fmaxf(acc[r][u] + bias_r[u], 0.f);
      if (ok) C[(size_t)row * HID + tx + 16 * u] = v;
      p = fmaf(v, wt_r[u], p);
    }
    if constexpr (TAU) {
      p += __shfl_down(p, 8);
      p += __shfl_down(p, 4);
      p += __shfl_down(p, 2);
      p += __shfl_down(p, 1);
      if (tx == 0) taured[ty * 8 + r] = p;
    }
  }
  if constexpr (TAU) {
    __syncthreads();
    if (tid < 128) {
      int row = i0 + tid;
      if (row < M) {
        float pre = taured[tid] + bt[0];
        float tau = (pre > 20.f) ? pre : log1pf(expf(pre));
        tau_out[row] = tau;
      }
    }
  }
}

// ---------------- mask + compaction ----------------
// np semantics: floor(1/tau).astype(int32) overflows to INT_MIN for 1/tau >= 2^31
// -> n_updates <= 0 -> NOT masked even though tau < 0.005.
__global__ void compact_kernel(const float* __restrict__ tau, int* __restrict__ list,
                               int* __restrict__ count, int N) {
  for (int i = blockIdx.x * blockDim.x + threadIdx.x; i < N; i += gridDim.x * blockDim.x) {
    float t = tau[i];
    if (t < 0.005f && (1.0f / t) < 2147483648.0f) {
      int p = atomicAdd(count, 1);
      list[p] = i;
    }
  }
}

// ---------------- masked GRU, 16 nodes / block ----------------
__global__ __launch_bounds__(256)
void gru_kernel(const float* __restrict__ diff, float* __restrict__ h,
                const int* __restrict__ list, const int* __restrict__ count,
                const float* __restrict__ WihT, const float* __restrict__ WhhT,
                const float* __restrict__ b_ih, const float* __restrict__ b_hh) {
  int cnt = *count;
  int base = blockIdx.x * 16;
  if (base >= cnt) return;
  __shared__ float dl[16][HID];
  __shared__ float hl[16][HID];
  __shared__ int ids[16];
  int tid = threadIdx.x;
  if (tid < 16) ids[tid] = (base + tid < cnt) ? list[base + tid] : -1;
  __syncthreads();
  #pragma unroll
  for (int q = 0; q < 8; ++q) {
    int f = q * 256 + tid;
    int r = f >> 7, c = f & 127;
    int id = ids[r];
    int src = (id >= 0) ? id : 0;
    dl[r][c] = diff[(size_t)src * HID + c];
    hl[r][c] = h[(size_t)src * HID + c];
  }
  __syncthreads();
  int tx = tid & 127, ty = tid >> 7;  // tx = output dim, ty -> rows ty*8..ty*8+7
  float air[8] = {}, aiz[8] = {}, ain[8] = {}, ahr[8] = {}, ahz[8] = {}, ahn[8] = {};
  for (int k = 0; k < HID; ++k) {
    float wir = WihT[k * 384 + tx];
    float wiz = WihT[k * 384 + 128 + tx];
    float win = WihT[k * 384 + 256 + tx];
    float whr = WhhT[k * 384 + tx];
    float whz = WhhT[k * 384 + 128 + tx];
    float whn = WhhT[k * 384 + 256 + tx];
    #pragma unroll
    for (int r = 0; r < 8; ++r) {
      float dk = dl[ty * 8 + r][k];
      float hk = hl[ty * 8 + r][k];
      air[r] = fmaf(dk, wir, air[r]);
      aiz[r] = fmaf(dk, wiz, aiz[r]);
      ain[r] = fmaf(dk, win, ain[r]);
      ahr[r] = fmaf(hk, whr, ahr[r]);
      ahz[r] = fmaf(hk, whz, ahz[r]);
      ahn[r] = fmaf(hk, whn, ahn[r]);
    }
  }
  float bir = b_ih[tx], biz = b_ih[128 + tx], bin = b_ih[256 + tx];
  float bhr = b_hh[tx], bhz = b_hh[128 + tx], bhn = b_hh[256 + tx];
  #pragma unroll
  for (int r = 0; r < 8; ++r) {
    int id = ids[ty * 8 + r];
    if (id < 0) continue;
    float rg = 1.f / (1.f + expf(-((air[r] + bir) + (ahr[r] + bhr))));
    float z  = 1.f / (1.f + expf(-((aiz[r] + biz) + (ahz[r] + bhz))));
    float n  = tanhf((ain[r] + bin) + rg * (ahn[r] + bhn));
    float hv = hl[ty * 8 + r][tx];
    h[(size_t)id * HID + tx] = (1.f - z) * n + z * hv;
  }
}

// ---------------- output head: out = h @ Wo^T + bo  (wave per node) ----------
__global__ void out_kernel(const float* __restrict__ h, const float* __restrict__ Wo,
                           const float* __restrict__ bo, float* __restrict__ out, int N) {
  int g = blockIdx.x * blockDim.x + threadIdx.x;
  int node = g >> 6;
  int lane = threadIdx.x & 63;
  if (node >= N) return;
  float h0 = h[(size_t)node * HID + lane];
  float h1 = h[(size_t)node * HID + 64 + lane];
  float s0 = h0 * Wo[lane] + h1 * Wo[64 + lane];
  float s1 = h0 * Wo[128 + lane] + h1 * Wo[192 + lane];
  for (int d = 32; d; d >>= 1) {
    s0 += __shfl_down(s0, d);
    s1 += __shfl_down(s1, d);
  }
  if (lane == 0) {
    out[(size_t)node * 2 + 0] = s0 + bo[0];
    out[(size_t)node * 2 + 1] = s1 + bo[1];
  }
}

extern "C" void kernel_launch(void* const* d_in, const int* in_sizes, int n_in,
                              void* d_out, int out_size, void* d_ws, size_t ws_size,
                              hipStream_t stream) {
  const float* x    = (const float*)d_in[0];
  const int*   ei   = (const int*)d_in[1];
  const float* W_in = (const float*)d_in[2];
  const float* b_in = (const float*)d_in[3];
  const float* Wd   = (const float*)d_in[4];
  const float* bd   = (const float*)d_in[5];
  const float* Wt   = (const float*)d_in[6];
  const float* bt   = (const float*)d_in[7];
  const float* W_ih = (const float*)d_in[8];
  const float* W_hh = (const float*)d_in[9];
  const float* b_ih = (const float*)d_in[10];
  const float* b_hh = (const float*)d_in[11];
  const float* Wo   = (const float*)d_in[12];
  const float* bo   = (const float*)d_in[13];

  const int N = in_sizes[0] / HID;      // 100000
  const int E = in_sizes[1] / 2;        // 1600000
  const int* rowp = ei;
  const int* colp = ei + E;

  // workspace carve-up (256B aligned)
  char* p = (char*)d_ws;
  auto alloc = [&](size_t bytes) { void* r = (void*)p; p += (bytes + 255) & ~(size_t)255; return r; };
  float* hA     = (float*)alloc((size_t)N * HID * 4);
  float* hB     = (float*)alloc((size_t)N * HID * 4);
  float* diff   = (float*)alloc((size_t)N * HID * 4);
  float* WinT   = (float*)alloc(128 * 128 * 4);
  float* WdT0   = (float*)alloc(256 * 128 * 4);
  float* WdT1   = (float*)alloc(256 * 128 * 4);
  float* WihT   = (float*)alloc(128 * 384 * 4);
  float* WhhT   = (float*)alloc(128 * 384 * 4);
  int*   deg    = (int*)alloc((size_t)N * 4);
  int*   offs   = (int*)alloc(((size_t)N + 1) * 4);
  int*   cursor = (int*)alloc((size_t)N * 4);
  int*   csrcol = (int*)alloc((size_t)E * 4);
  float* tau0   = (float*)alloc((size_t)N * 4);
  int*   list   = (int*)alloc((size_t)N * 4);
  int*   count  = (int*)alloc(256);

  float* out_ptr = (float*)d_out;            // [N,2] flat
  float* tau_out = (float*)d_out + (size_t)N * 2;  // [N]

  // weight transposes
  transpose_kernel<<<(128 * 128 + 255) / 256, 256, 0, stream>>>(W_in, WinT, 128, 128);
  transpose_kernel<<<(128 * 256 + 255) / 256, 256, 0, stream>>>(Wd, WdT0, 128, 256);
  transpose_kernel<<<(128 * 256 + 255) / 256, 256, 0, stream>>>(Wd + 128 * 256, WdT1, 128, 256);
  transpose_kernel<<<(384 * 128 + 255) / 256, 256, 0, stream>>>(W_ih, WihT, 384, 128);
  transpose_kernel<<<(384 * 128 + 255) / 256, 256, 0, stream>>>(W_hh, WhhT, 384, 128);

  // CSR build (reused by both layers)
  hipMemsetAsync(deg, 0, (size_t)N * 4, stream);
  hist_kernel<<<(E + 255) / 256, 256, 0, stream>>>(rowp, deg, E);
  scan_kernel<<<1, 1024, 0, stream>>>(deg, offs, cursor, N);
  fill_kernel<<<(E + 255) / 256, 256, 0, stream>>>(rowp, colp, cursor, csrcol, E);

  const int gemm_blocks = (N + 127) / 128;
  const int agg_blocks = (N + 3) / 4;

  // input layer: hA = relu(x @ Win^T + b_in)
  gemm_kernel<false><<<gemm_blocks, 256, 0, stream>>>(
      x, nullptr, WinT, b_in, hA, N, 4, nullptr, nullptr, nullptr);

  // ---- layer 0 ----
  aggregate_kernel<<<agg_blocks, 256, 0, stream>>>(hA, offs, csrcol, diff, N);
  gemm_kernel<true><<<gemm_blocks, 256, 0, stream>>>(
      hA, diff, WdT0, bd, hB, N, 8, Wt, bt, tau0);
  hipMemsetAsync(count, 0, 4, stream);
  compact_kernel<<<(N + 255) / 256, 256, 0, stream>>>(tau0, list, count, N);
  gru_kernel<<<(N + 15) / 16, 256, 0, stream>>>(diff, hB, list, count, WihT, WhhT, b_ih, b_hh);

  // ---- layer 1 ----
  aggregate_kernel<<<agg_blocks, 256, 0, stream>>>(hB, offs, csrcol, diff, N);
  gemm_kernel<true><<<gemm_blocks, 256, 0, stream>>>(
      hB, diff, WdT1, bd + 128, hA, N, 8, Wt, bt, tau_out);
  hipMemsetAsync(count, 0, 4, stream);
  compact_kernel<<<(N + 255) / 256, 256, 0, stream>>>(tau_out, list, count, N);
  gru_kernel<<<(N + 15) / 16, 256, 0, stream>>>(diff, hA, list, count, WihT, WhhT, b_ih, b_hh);

  // output head
  out_kernel<<<((size_t)N * 64 + 255) / 256, 256, 0, stream>>>(hA, Wo, bo, out_ptr, N);
}

// Round 3
// 942.454 us; speedup vs baseline: 1.5835x; 1.2142x over previous
//
#include <hip/hip_runtime.h>
#include <cstdint>
#include <cstddef>

#define HID 128

// ---------------- small transpose (weights, once per launch) ----------------
__global__ void transpose_kernel(const float* __restrict__ src, float* __restrict__ dst,
                                 int R, int C) {
  int i = blockIdx.x * blockDim.x + threadIdx.x;
  if (i < R * C) {
    int r = i / C, c = i - r * C;
    dst[c * R + r] = src[i];
  }
}

// ---------------- CSR build ----------------
__global__ void hist_kernel(const int* __restrict__ row, int* __restrict__ deg, int E) {
  for (int e = blockIdx.x * blockDim.x + threadIdx.x; e < E; e += gridDim.x * blockDim.x)
    atomicAdd(&deg[row[e]], 1);
}

// 3-phase multi-block exclusive scan (replaces round-2's 232us single-block scan:
// 0.15% occupancy, latency-serialized. These 3 kernels are each ~2-5us).
__global__ __launch_bounds__(256)
void block_sum_kernel(const int* __restrict__ deg, int* __restrict__ blocksums,
                      int N, int per_block) {
  int b = blockIdx.x;
  int start = b * per_block;
  int end = min(start + per_block, N);
  int s = 0;
  for (int i = start + (int)threadIdx.x; i < end; i += 256) s += deg[i];
  __shared__ int sw[4];
  #pragma unroll
  for (int d = 32; d; d >>= 1) s += __shfl_down(s, d);
  int wave = threadIdx.x >> 6, lane = threadIdx.x & 63;
  if (lane == 0) sw[wave] = s;
  __syncthreads();
  if (threadIdx.x == 0) blocksums[b] = sw[0] + sw[1] + sw[2] + sw[3];
}

__global__ __launch_bounds__(256)
void scan_blocksums_kernel(const int* __restrict__ blocksums, int* __restrict__ blockoffs,
                           int* __restrict__ offsets, int N, int nblocks) {
  __shared__ int sd[256];
  int t = threadIdx.x;
  int v = (t < nblocks) ? blocksums[t] : 0;
  sd[t] = v;
  __syncthreads();
  for (int off = 1; off < 256; off <<= 1) {
    int u = (t >= off) ? sd[t - off] : 0;
    __syncthreads();
    sd[t] += u;
    __syncthreads();
  }
  blockoffs[t] = sd[t] - v;  // exclusive
  if (t == 255) offsets[N] = sd[255];
}

__global__ __launch_bounds__(256)
void block_scan_kernel(const int* __restrict__ deg, const int* __restrict__ blockoffs,
                       int* __restrict__ offsets, int* __restrict__ cursor,
                       int N, int per_block) {
  int b = blockIdx.x;
  int start = b * per_block;
  int end = min(start + per_block, N);
  int t = threadIdx.x;
  int chunk = (per_block + 255) >> 8;
  int cb = start + t * chunk;
  int ce = min(cb + chunk, end);
  int s = 0;
  for (int i = cb; i < ce; ++i) s += deg[i];
  __shared__ int sd[256];
  sd[t] = s;
  __syncthreads();
  for (int off = 1; off < 256; off <<= 1) {
    int u = (t >= off) ? sd[t - off] : 0;
    __syncthreads();
    sd[t] += u;
    __syncthreads();
  }
  int run = blockoffs[b] + sd[t] - s;
  for (int i = cb; i < ce; ++i) {
    offsets[i] = run; cursor[i] = run;
    run += deg[i];
  }
}

__global__ void fill_kernel(const int* __restrict__ row, const int* __restrict__ col,
                            int* __restrict__ cursor, int* __restrict__ csr_col, int E) {
  for (int e = blockIdx.x * blockDim.x + threadIdx.x; e < E; e += gridDim.x * blockDim.x) {
    int r = row[e];
    int p = atomicAdd(&cursor[r], 1);
    csr_col[p] = col[e];
  }
}

// ---------------- edge aggregation: diff[i][d] = sum_e |h[i][d]-h[col][d]| ----
// One wave per node; lane owns dims {lane, lane+64}. Neighbor ids staged into
// registers (coalesced csr_col load + __shfl broadcast); 4-edge unroll gives
// 8 outstanding gathers/lane.
__global__ __launch_bounds__(256)
void aggregate_kernel(const float* __restrict__ h, const int* __restrict__ offsets,
                      const int* __restrict__ csr_col, float* __restrict__ diff,
                      int N) {
  int wave = threadIdx.x >> 6;
  int lane = threadIdx.x & 63;
  int node = blockIdx.x * 4 + wave;
  if (node >= N) return;
  int start = offsets[node], end = offsets[node + 1];
  int deg = end - start;
  const float* hrow = h + (size_t)node * HID;
  float hv0 = hrow[lane], hv1 = hrow[lane + 64];
  float a0 = 0.f, a1 = 0.f;

  int batch = min(deg, 64);
  int myc = (lane < batch) ? csr_col[start + lane] : 0;
  int j = 0;
  for (; j + 4 <= batch; j += 4) {
    int c0 = __shfl(myc, j + 0);
    int c1 = __shfl(myc, j + 1);
    int c2 = __shfl(myc, j + 2);
    int c3 = __shfl(myc, j + 3);
    const float* p0 = h + (size_t)c0 * HID;
    const float* p1 = h + (size_t)c1 * HID;
    const float* p2 = h + (size_t)c2 * HID;
    const float* p3 = h + (size_t)c3 * HID;
    float x00 = p0[lane], x01 = p0[lane + 64];
    float x10 = p1[lane], x11 = p1[lane + 64];
    float x20 = p2[lane], x21 = p2[lane + 64];
    float x30 = p3[lane], x31 = p3[lane + 64];
    a0 += fabsf(hv0 - x00) + fabsf(hv0 - x10) + fabsf(hv0 - x20) + fabsf(hv0 - x30);
    a1 += fabsf(hv1 - x01) + fabsf(hv1 - x11) + fabsf(hv1 - x21) + fabsf(hv1 - x31);
  }
  for (; j < batch; ++j) {
    int c = __shfl(myc, j);
    const float* p = h + (size_t)c * HID;
    a0 += fabsf(hv0 - p[lane]);
    a1 += fabsf(hv1 - p[lane + 64]);
  }
  for (int e = start + 64; e < end; ++e) {
    int c = csr_col[e];
    const float* p = h + (size_t)c * HID;
    a0 += fabsf(hv0 - p[lane]);
    a1 += fabsf(hv1 - p[lane + 64]);
  }
  diff[(size_t)node * HID + lane] = a0;
  diff[(size_t)node * HID + lane + 64] = a1;
}

// ---------------- tiled fp32 GEMM: C = relu([A1|A2] @ BT + bias), opt tau ----
template<bool TAU>
__global__ __launch_bounds__(256)
void gemm_kernel(const float* __restrict__ A1, const float* __restrict__ A2,
                 const float* __restrict__ BT, const float* __restrict__ bias,
                 float* __restrict__ C, int M, int nchunks,
                 const float* __restrict__ Wt, const float* __restrict__ bt,
                 float* __restrict__ tau_out) {
  __shared__ float As[32][132];   // [k][i], padded leading dim
  __shared__ float Bs[32][128];   // [k][c]
  __shared__ float taured[128];
  int tid = threadIdx.x;
  int tx = tid & 15;   // col group: cols tx + 16*u
  int ty = tid >> 4;   // row group: rows ty*8 + r
  int i0 = blockIdx.x * 128;
  float acc[8][8] = {};

  for (int kc = 0; kc < nchunks; ++kc) {
    const float* A = (kc < 4) ? A1 : A2;
    int ksrc = (kc & 3) * 32;
    int kglob = kc * 32;
    #pragma unroll
    for (int q = 0; q < 4; ++q) {     // stage A (transposed into LDS)
      int f = q * 256 + tid;
      int i = f >> 3;
      int kq = (f & 7) << 2;
      int ig = i0 + i; if (ig >= M) ig = M - 1;
      float4 v = *(const float4*)(A + (size_t)ig * HID + ksrc + kq);
      As[kq + 0][i] = v.x; As[kq + 1][i] = v.y;
      As[kq + 2][i] = v.z; As[kq + 3][i] = v.w;
    }
    #pragma unroll
    for (int q = 0; q < 4; ++q) {     // stage B
      int f = q * 256 + tid;
      int k = f >> 5; int c4 = (f & 31) << 2;
      *(float4*)&Bs[k][c4] = *(const float4*)(BT + (size_t)(kglob + k) * HID + c4);
    }
    __syncthreads();
    #pragma unroll
    for (int k = 0; k < 32; ++k) {
      float a[8], b[8];
      const float4* ap = (const float4*)&As[k][ty * 8];
      float4 a0 = ap[0], a1 = ap[1];
      a[0]=a0.x; a[1]=a0.y; a[2]=a0.z; a[3]=a0.w;
      a[4]=a1.x; a[5]=a1.y; a[6]=a1.z; a[7]=a1.w;
      #pragma unroll
      for (int u = 0; u < 8; ++u) b[u] = Bs[k][tx + 16 * u];
      #pragma unroll
      for (int r = 0; r < 8; ++r)
        #pragma unroll
        for (int u = 0; u < 8; ++u)
          acc[r][u] = fmaf(a[r], b[u], acc[r][u]);
    }
    __syncthreads();
  }

  float bias_r[8], wt_r[8];
  #pragma unroll
  for (int u = 0; u < 8; ++u) { bias_r[u] = bias[tx + 16 * u]; wt_r[u] = 0.f; }
  if constexpr (TAU) {
    #pragma unroll
    for (int u = 0; u < 8; ++u) wt_r[u] = Wt[tx + 16 * u];
  }
  #pragma unroll
  for (int r = 0; r < 8; ++r) {
    int row = i0 + ty * 8 + r;
    bool ok = row < M;
    float p = 0.f;
    #pragma unroll
    for (int u = 0; u < 8; ++u) {
      float v = fmaxf(acc[r][u] + bias_r[u], 0.f);
      if (ok) C[(size_t)row * HID + tx + 16 * u] = v;
      p = fmaf(v, wt_r[u], p);
    }
    if constexpr (TAU) {
      p += __shfl_down(p, 8);
      p += __shfl_down(p, 4);
      p += __shfl_down(p, 2);
      p += __shfl_down(p, 1);
      if (tx == 0) taured[ty * 8 + r] = p;
    }
  }
  if constexpr (TAU) {
    __syncthreads();
    if (tid < 128) {
      int row = i0 + tid;
      if (row < M) {
        float pre = taured[tid] + bt[0];
        float tau = (pre > 20.f) ? pre : log1pf(expf(pre));
        tau_out[row] = tau;
      }
    }
  }
}

// ---------------- mask + compaction ----------------
// np semantics: floor(1/tau).astype(int32) overflows to INT_MIN for 1/tau >= 2^31
// -> n_updates <= 0 -> NOT masked even though tau < 0.005.
__global__ void compact_kernel(const float* __restrict__ tau, int* __restrict__ list,
                               int* __restrict__ count, int N) {
  for (int i = blockIdx.x * blockDim.x + threadIdx.x; i < N; i += gridDim.x * blockDim.x) {
    float t = tau[i];
    if (t < 0.005f && (1.0f / t) < 2147483648.0f) {
      int p = atomicAdd(count, 1);
      list[p] = i;
    }
  }
}

// ---------------- masked GRU, 16 nodes / block ----------------
__global__ __launch_bounds__(256)
void gru_kernel(const float* __restrict__ diff, float* __restrict__ h,
                const int* __restrict__ list, const int* __restrict__ count,
                const float* __restrict__ WihT, const float* __restrict__ WhhT,
                const float* __restrict__ b_ih, const float* __restrict__ b_hh) {
  int cnt = *count;
  int base = blockIdx.x * 16;
  if (base >= cnt) return;
  __shared__ float dl[16][HID];
  __shared__ float hl[16][HID];
  __shared__ int ids[16];
  int tid = threadIdx.x;
  if (tid < 16) ids[tid] = (base + tid < cnt) ? list[base + tid] : -1;
  __syncthreads();
  #pragma unroll
  for (int q = 0; q < 8; ++q) {
    int f = q * 256 + tid;
    int r = f >> 7, c = f & 127;
    int id = ids[r];
    int src = (id >= 0) ? id : 0;
    dl[r][c] = diff[(size_t)src * HID + c];
    hl[r][c] = h[(size_t)src * HID + c];
  }
  __syncthreads();
  int tx = tid & 127, ty = tid >> 7;
  float air[8] = {}, aiz[8] = {}, ain[8] = {}, ahr[8] = {}, ahz[8] = {}, ahn[8] = {};
  for (int k = 0; k < HID; ++k) {
    float wir = WihT[k * 384 + tx];
    float wiz = WihT[k * 384 + 128 + tx];
    float win = WihT[k * 384 + 256 + tx];
    float whr = WhhT[k * 384 + tx];
    float whz = WhhT[k * 384 + 128 + tx];
    float whn = WhhT[k * 384 + 256 + tx];
    #pragma unroll
    for (int r = 0; r < 8; ++r) {
      float dk = dl[ty * 8 + r][k];
      float hk = hl[ty * 8 + r][k];
      air[r] = fmaf(dk, wir, air[r]);
      aiz[r] = fmaf(dk, wiz, aiz[r]);
      ain[r] = fmaf(dk, win, ain[r]);
      ahr[r] = fmaf(hk, whr, ahr[r]);
      ahz[r] = fmaf(hk, whz, ahz[r]);
      ahn[r] = fmaf(hk, whn, ahn[r]);
    }
  }
  float bir = b_ih[tx], biz = b_ih[128 + tx], bin = b_ih[256 + tx];
  float bhr = b_hh[tx], bhz = b_hh[128 + tx], bhn = b_hh[256 + tx];
  #pragma unroll
  for (int r = 0; r < 8; ++r) {
    int id = ids[ty * 8 + r];
    if (id < 0) continue;
    float rg = 1.f / (1.f + expf(-((air[r] + bir) + (ahr[r] + bhr))));
    float z  = 1.f / (1.f + expf(-((aiz[r] + biz) + (ahz[r] + bhz))));
    float n  = tanhf((ain[r] + bin) + rg * (ahn[r] + bhn));
    float hv = hl[ty * 8 + r][tx];
    h[(size_t)id * HID + tx] = (1.f - z) * n + z * hv;
  }
}

// ---------------- output head: out = h @ Wo^T + bo  (wave per node) ----------
__global__ void out_kernel(const float* __restrict__ h, const float* __restrict__ Wo,
                           const float* __restrict__ bo, float* __restrict__ out, int N) {
  int g = blockIdx.x * blockDim.x + threadIdx.x;
  int node = g >> 6;
  int lane = threadIdx.x & 63;
  if (node >= N) return;
  float h0 = h[(size_t)node * HID + lane];
  float h1 = h[(size_t)node * HID + 64 + lane];
  float s0 = h0 * Wo[lane] + h1 * Wo[64 + lane];
  float s1 = h0 * Wo[128 + lane] + h1 * Wo[192 + lane];
  for (int d = 32; d; d >>= 1) {
    s0 += __shfl_down(s0, d);
    s1 += __shfl_down(s1, d);
  }
  if (lane == 0) {
    out[(size_t)node * 2 + 0] = s0 + bo[0];
    out[(size_t)node * 2 + 1] = s1 + bo[1];
  }
}

extern "C" void kernel_launch(void* const* d_in, const int* in_sizes, int n_in,
                              void* d_out, int out_size, void* d_ws, size_t ws_size,
                              hipStream_t stream) {
  const float* x    = (const float*)d_in[0];
  const int*   ei   = (const int*)d_in[1];
  const float* W_in = (const float*)d_in[2];
  const float* b_in = (const float*)d_in[3];
  const float* Wd   = (const float*)d_in[4];
  const float* bd   = (const float*)d_in[5];
  const float* Wt   = (const float*)d_in[6];
  const float* bt   = (const float*)d_in[7];
  const float* W_ih = (const float*)d_in[8];
  const float* W_hh = (const float*)d_in[9];
  const float* b_ih = (const float*)d_in[10];
  const float* b_hh = (const float*)d_in[11];
  const float* Wo   = (const float*)d_in[12];
  const float* bo   = (const float*)d_in[13];

  const int N = in_sizes[0] / HID;      // 100000
  const int E = in_sizes[1] / 2;        // 1600000
  const int* rowp = ei;
  const int* colp = ei + E;

  // workspace carve-up (256B aligned)
  char* p = (char*)d_ws;
  auto alloc = [&](size_t bytes) { void* r = (void*)p; p += (bytes + 255) & ~(size_t)255; return r; };
  float* hA     = (float*)alloc((size_t)N * HID * 4);
  float* hB     = (float*)alloc((size_t)N * HID * 4);
  float* diff   = (float*)alloc((size_t)N * HID * 4);
  float* WinT   = (float*)alloc(128 * 128 * 4);
  float* WdT0   = (float*)alloc(256 * 128 * 4);
  float* WdT1   = (float*)alloc(256 * 128 * 4);
  float* WihT   = (float*)alloc(128 * 384 * 4);
  float* WhhT   = (float*)alloc(128 * 384 * 4);
  int*   deg    = (int*)alloc((size_t)N * 4);
  int*   offs   = (int*)alloc(((size_t)N + 1) * 4);
  int*   cursor = (int*)alloc((size_t)N * 4);
  int*   csrcol = (int*)alloc((size_t)E * 4);
  float* tau0   = (float*)alloc((size_t)N * 4);
  int*   list   = (int*)alloc((size_t)N * 4);
  int*   count  = (int*)alloc(256);
  int*   blocksums = (int*)alloc(256 * 4);
  int*   blockoffs = (int*)alloc(256 * 4);

  float* out_ptr = (float*)d_out;            // [N,2] flat
  float* tau_out = (float*)d_out + (size_t)N * 2;  // [N]

  // weight transposes
  transpose_kernel<<<(128 * 128 + 255) / 256, 256, 0, stream>>>(W_in, WinT, 128, 128);
  transpose_kernel<<<(128 * 256 + 255) / 256, 256, 0, stream>>>(Wd, WdT0, 128, 256);
  transpose_kernel<<<(128 * 256 + 255) / 256, 256, 0, stream>>>(Wd + 128 * 256, WdT1, 128, 256);
  transpose_kernel<<<(384 * 128 + 255) / 256, 256, 0, stream>>>(W_ih, WihT, 384, 128);
  transpose_kernel<<<(384 * 128 + 255) / 256, 256, 0, stream>>>(W_hh, WhhT, 384, 128);

  // CSR build (reused by both layers)
  hipMemsetAsync(deg, 0, (size_t)N * 4, stream);
  hist_kernel<<<(E + 255) / 256, 256, 0, stream>>>(rowp, deg, E);
  int per_block = (N + 255) / 256;
  block_sum_kernel<<<256, 256, 0, stream>>>(deg, blocksums, N, per_block);
  scan_blocksums_kernel<<<1, 256, 0, stream>>>(blocksums, blockoffs, offs, N, 256);
  block_scan_kernel<<<256, 256, 0, stream>>>(deg, blockoffs, offs, cursor, N, per_block);
  fill_kernel<<<(E + 255) / 256, 256, 0, stream>>>(rowp, colp, cursor, csrcol, E);

  const int gemm_blocks = (N + 127) / 128;
  const int agg_blocks = (N + 3) / 4;

  // input layer: hA = relu(x @ Win^T + b_in)
  gemm_kernel<false><<<gemm_blocks, 256, 0, stream>>>(
      x, nullptr, WinT, b_in, hA, N, 4, nullptr, nullptr, nullptr);

  // ---- layer 0 ----
  aggregate_kernel<<<agg_blocks, 256, 0, stream>>>(hA, offs, csrcol, diff, N);
  gemm_kernel<true><<<gemm_blocks, 256, 0, stream>>>(
      hA, diff, WdT0, bd, hB, N, 8, Wt, bt, tau0);
  hipMemsetAsync(count, 0, 4, stream);
  compact_kernel<<<(N + 255) / 256, 256, 0, stream>>>(tau0, list, count, N);
  gru_kernel<<<(N + 15) / 16, 256, 0, stream>>>(diff, hB, list, count, WihT, WhhT, b_ih, b_hh);

  // ---- layer 1 ----
  aggregate_kernel<<<agg_blocks, 256, 0, stream>>>(hB, offs, csrcol, diff, N);
  gemm_kernel<true><<<gemm_blocks, 256, 0, stream>>>(
      hB, diff, WdT1, bd + 128, hA, N, 8, Wt, bt, tau_out);
  hipMemsetAsync(count, 0, 4, stream);
  compact_kernel<<<(N + 255) / 256, 256, 0, stream>>>(tau_out, list, count, N);
  gru_kernel<<<(N + 15) / 16, 256, 0, stream>>>(diff, hA, list, count, WihT, WhhT, b_ih, b_hh);

  // output head
  out_kernel<<<((size_t)N * 64 + 255) / 256, 256, 0, stream>>>(hA, Wo, bo, out_ptr, N);
}